// Round 8
// baseline (67.802 us; speedup 1.0000x reference)
//
#include <hip/hip_runtime.h>

#define N_NODES 100000
#define N_EDGES 6400000

#define HSCALE 4096.0f           // 2^12 fixed point for h
#define HCLAMP 63.0f             // |hfix| <= 258048 < 2^18; bias 2^19 -> 20 bits
#define HBIAS  (1 << 19)

// ---- Partition geometry -----------------------------------------------------
#define QBIN       1600          // nodes per bin (non-pow2; /% by magic-mul)
#define NQBINS     63            // 63*1600 = 100800 >= 100000; ~1 lane/addr in wave
#define PBLOCKS    512           // 3125 quads per block, exact
#define PTHREADS   1024
#define LCAP       288           // staging entries/bucket: mean 200, +6.3 sigma
#define GBINCAP    110000        // records per bin: mean 102400 (+24 sigma)
#define NQBLK      16            // accumulate blocks per bin -> grid 1008
#define QTHREADS   1024

// ---------------------------------------------------------------------------
// Kernel A: per-node tiny MLP -> fixed-point int (scale 2^12, clamp +-63).
// ---------------------------------------------------------------------------
__global__ void mlp_kernel(const float* __restrict__ x,
                           const float* __restrict__ W1,
                           const float* __restrict__ b1,
                           const float* __restrict__ W2,
                           const float* __restrict__ b2,
                           int* __restrict__ hfix, int n) {
    int i = blockIdx.x * blockDim.x + threadIdx.x;
    if (i >= n) return;
    float xv = x[i];
    float acc = b2[0];
#pragma unroll
    for (int k = 0; k < 16; ++k) {
        float t = fmaxf(W1[k] * xv + b1[k], 0.0f);
        acc = fmaf(W2[k], t, acc);
    }
    acc = fminf(fmaxf(acc, -HCLAMP), HCLAMP);
    hfix[i] = __float2int_rn(acc * HSCALE);
}

// ---------------------------------------------------------------------------
// Pass P: single-read edge partition.  rec = (dst%1600 << 20) | (hfix+2^19).
// 63 buckets -> a wave's 64 scnt atomics spread over 63 LDS addresses
// (avg 1 lane/addr) instead of 25 -> no same-address serialization.
// 71KB LDS staging -> 2 blocks/CU (32 waves = 100% occupancy).
// ---------------------------------------------------------------------------
__global__ __launch_bounds__(PTHREADS)
void partition_kernel(const int* __restrict__ src,
                      const int* __restrict__ dst,
                      const int* __restrict__ hfix,
                      unsigned* __restrict__ recs,      // [NQBINS * GBINCAP]
                      unsigned* __restrict__ cursor) {  // [NQBINS], zeroed
    extern __shared__ unsigned sbuf[];                  // NQBINS * LCAP u32
    __shared__ unsigned scnt[NQBINS];
    __shared__ unsigned sbase[NQBINS];
    const int tid = threadIdx.x;
    if (tid < NQBINS) scnt[tid] = 0u;
    __syncthreads();

    const int quads = (N_EDGES / 4) / PBLOCKS;          // 3125 exact
    const int4* __restrict__ s4 = (const int4*)src + (size_t)blockIdx.x * quads;
    const int4* __restrict__ d4 = (const int4*)dst + (size_t)blockIdx.x * quads;

    for (int i = tid; i < quads; i += PTHREADS) {
        int4 d = d4[i];
        int4 s = s4[i];
        // Independent gathers + bucket computes first (overlapping chains).
        unsigned v0 = (unsigned)(hfix[s.x] + HBIAS);
        unsigned v1 = (unsigned)(hfix[s.y] + HBIAS);
        unsigned v2 = (unsigned)(hfix[s.z] + HBIAS);
        unsigned v3 = (unsigned)(hfix[s.w] + HBIAS);
        int b0 = d.x / QBIN, b1 = d.y / QBIN;            // magic-mul division
        int b2 = d.z / QBIN, b3 = d.w / QBIN;
        unsigned rec0 = ((unsigned)(d.x - b0 * QBIN) << 20) | v0;
        unsigned rec1 = ((unsigned)(d.y - b1 * QBIN) << 20) | v1;
        unsigned rec2 = ((unsigned)(d.z - b2 * QBIN) << 20) | v2;
        unsigned rec3 = ((unsigned)(d.w - b3 * QBIN) << 20) | v3;
        unsigned sl0 = atomicAdd(&scnt[b0], 1u);
        unsigned sl1 = atomicAdd(&scnt[b1], 1u);
        unsigned sl2 = atomicAdd(&scnt[b2], 1u);
        unsigned sl3 = atomicAdd(&scnt[b3], 1u);
#define STORE(B, SL, REC)                                                     \
        if ((SL) < (unsigned)LCAP) {                                          \
            sbuf[(B) * LCAP + (SL)] = (REC);                                  \
        } else {                                                              \
            unsigned g = atomicAdd(&cursor[B], 1u);                           \
            if (g < (unsigned)GBINCAP) recs[(size_t)(B) * GBINCAP + g] = (REC);\
        }
        STORE(b0, sl0, rec0);
        STORE(b1, sl1, rec1);
        STORE(b2, sl2, rec2);
        STORE(b3, sl3, rec3);
#undef STORE
    }
    __syncthreads();

    // Reserve global ranges (63 atomics/block), flush buckets coalesced.
    if (tid < NQBINS) {
        unsigned m = min(scnt[tid], (unsigned)LCAP);
        sbase[tid] = atomicAdd(&cursor[tid], m);
    }
    __syncthreads();
    for (int b = 0; b < NQBINS; ++b) {
        unsigned m = min(scnt[b], (unsigned)LCAP);
        unsigned bs = sbase[b];
        for (unsigned t = tid; t < m; t += PTHREADS) {
            unsigned g = bs + t;
            if (g < (unsigned)GBINCAP)
                recs[(size_t)b * GBINCAP + g] = sbuf[b * LCAP + t];
        }
    }
}

// ---------------------------------------------------------------------------
// Pass Q: per-bin accumulation.  Coalesced u32 record reads, no gathers.
// acc is 6.4KB -> high occupancy.  Packed u32: sum(24b) | count(8b);
// per (node, block) count ~ Poisson(4) << 255, |sum| << 2^23.
// ---------------------------------------------------------------------------
__global__ __launch_bounds__(QTHREADS)
void accumulate_kernel(const unsigned* __restrict__ recs,
                       const unsigned* __restrict__ cursor,
                       unsigned* __restrict__ partials) {
    __shared__ unsigned acc[QBIN];   // 6.4 KB
    const int b = blockIdx.x / NQBLK;
    const int j = blockIdx.x % NQBLK;
    const int tid = threadIdx.x;
    for (int k = tid; k < QBIN; k += QTHREADS) acc[k] = 0u;
    __syncthreads();

    const unsigned total = min(cursor[b], (unsigned)GBINCAP);
    const unsigned* __restrict__ base = recs + (size_t)b * GBINCAP;
    for (unsigned i = (unsigned)j * QTHREADS + tid; i < total;
         i += (unsigned)NQBLK * QTHREADS) {
        unsigned rec = base[i];
        unsigned rel = rec >> 20;
        int hf = (int)(rec & 0xFFFFFu) - HBIAS;
        atomicAdd(&acc[rel], (((unsigned)hf) << 8) + 1u);
    }
    __syncthreads();

    unsigned* __restrict__ outp = partials + (size_t)blockIdx.x * QBIN;
    for (int k = tid; k < QBIN; k += QTHREADS) outp[k] = acc[k];
}

// ---------------------------------------------------------------------------
// Pass F: reduce NQBLK partials per node, decode, mean, apply Ws.
// ---------------------------------------------------------------------------
__global__ void finalize_part(const unsigned* __restrict__ partials,
                              const float* __restrict__ Ws,
                              float* __restrict__ out, int n) {
    int i = blockIdx.x * blockDim.x + threadIdx.x;
    if (i >= n) return;
    const int bin = i / QBIN;        // compile-time divisor -> magic mul
    const int local = i - bin * QBIN;
    int cnt = 0, sum = 0;
#pragma unroll
    for (int j = 0; j < NQBLK; ++j) {
        unsigned p = partials[(size_t)(bin * NQBLK + j) * QBIN + local];
        cnt += (int)(p & 0xFFu);
        sum += ((int)p) >> 8;
    }
    float mean = ((float)sum * (1.0f / HSCALE)) / (float)max(cnt, 1);
    float2 o;
    o.x = mean * Ws[0];
    o.y = mean * Ws[1];
    ((float2*)out)[i] = o;
}

// ===========================================================================
// Fallback 1: LDS-binned multi-pass scatter, 3 bins x 33792 (R5).
// ===========================================================================
template <int TBIN, int TNBINS>
__global__ __launch_bounds__(1024)
void scatter_binned(const int* __restrict__ src,
                    const int* __restrict__ dst,
                    const int* __restrict__ hfix,
                    unsigned* __restrict__ partials,
                    int n4_per_slice) {
    extern __shared__ unsigned acc[];
    const int bin   = blockIdx.x % TNBINS;
    const int slice = blockIdx.x / TNBINS;
    const int tid = threadIdx.x;
    for (int j = tid; j < TBIN; j += 1024) acc[j] = 0u;
    __syncthreads();
    const int bin_lo = bin * TBIN;
    const int4* __restrict__ s4 = (const int4*)src + (size_t)slice * n4_per_slice;
    const int4* __restrict__ d4 = (const int4*)dst + (size_t)slice * n4_per_slice;
#define PROC(dd, ss)                                                          \
    {                                                                         \
        unsigned r;                                                           \
        r = (unsigned)((dd).x - bin_lo);                                      \
        if (r < (unsigned)TBIN)                                               \
            atomicAdd(&acc[r], (((unsigned)hfix[(ss).x]) << 8) + 1u);         \
        r = (unsigned)((dd).y - bin_lo);                                      \
        if (r < (unsigned)TBIN)                                               \
            atomicAdd(&acc[r], (((unsigned)hfix[(ss).y]) << 8) + 1u);         \
        r = (unsigned)((dd).z - bin_lo);                                      \
        if (r < (unsigned)TBIN)                                               \
            atomicAdd(&acc[r], (((unsigned)hfix[(ss).z]) << 8) + 1u);         \
        r = (unsigned)((dd).w - bin_lo);                                      \
        if (r < (unsigned)TBIN)                                               \
            atomicAdd(&acc[r], (((unsigned)hfix[(ss).w]) << 8) + 1u);         \
    }
    for (int i = tid; i < n4_per_slice; i += 2048) {
        int4 d0 = d4[i];
        int4 s0 = s4[i];
        const int i1 = i + 1024;
        int4 d1, s1;
        const bool have1 = i1 < n4_per_slice;
        if (have1) { d1 = d4[i1]; s1 = s4[i1]; }
        PROC(d0, s0);
        if (have1) PROC(d1, s1);
    }
#undef PROC
    __syncthreads();
    unsigned* __restrict__ outp = partials + (size_t)blockIdx.x * TBIN;
    for (int j = tid; j < TBIN; j += 1024) outp[j] = acc[j];
}

template <int TBIN, int TNBINS>
__global__ void finalize_binned(const unsigned* __restrict__ partials,
                                const float* __restrict__ Ws,
                                float* __restrict__ out, int n, int nslices) {
    int i = blockIdx.x * blockDim.x + threadIdx.x;
    if (i >= n) return;
    const int bin = i / TBIN;
    const int local = i % TBIN;
    int cnt = 0, sum = 0;
    for (int s = 0; s < nslices; ++s) {
        unsigned p = partials[(size_t)(s * TNBINS + bin) * TBIN + local];
        cnt += (int)(p & 0xFFu);
        sum += ((int)p) >> 8;
    }
    float mean = ((float)sum * (1.0f / HSCALE)) / (float)max(cnt, 1);
    float2 o;
    o.x = mean * Ws[0];
    o.y = mean * Ws[1];
    ((float2*)out)[i] = o;
}

// ===========================================================================
// Fallback 2: one packed u64 global atomic per edge.
// ===========================================================================
__global__ void scatter_atomic(const int* __restrict__ src,
                               const int* __restrict__ dst,
                               const int* __restrict__ hfix,
                               unsigned long long* __restrict__ packed) {
    int tid = blockIdx.x * blockDim.x + threadIdx.x;
    int stride = gridDim.x * blockDim.x;
    const int4* __restrict__ src4 = (const int4*)src;
    const int4* __restrict__ dst4 = (const int4*)dst;
    const int n4 = N_EDGES / 4;
    for (int e = tid; e < n4; e += stride) {
        int4 s = src4[e];
        int4 d = dst4[e];
        long long h0 = hfix[s.x], h1 = hfix[s.y], h2 = hfix[s.z], h3 = hfix[s.w];
        atomicAdd(&packed[d.x], ((unsigned long long)(h0 << 20)) + 1ull);
        atomicAdd(&packed[d.y], ((unsigned long long)(h1 << 20)) + 1ull);
        atomicAdd(&packed[d.z], ((unsigned long long)(h2 << 20)) + 1ull);
        atomicAdd(&packed[d.w], ((unsigned long long)(h3 << 20)) + 1ull);
    }
}

__global__ void finalize_atomic(const unsigned long long* __restrict__ packed,
                                const float* __restrict__ Ws,
                                float* __restrict__ out, int n) {
    int i = blockIdx.x * blockDim.x + threadIdx.x;
    if (i >= n) return;
    long long p = (long long)packed[i];
    int cnt = (int)(p & 0xFFFFFll);
    long long sf = p >> 20;
    float mean = ((float)sf * (1.0f / HSCALE)) / (float)max(cnt, 1);
    float2 o;
    o.x = mean * Ws[0];
    o.y = mean * Ws[1];
    ((float2*)out)[i] = o;
}

extern "C" void kernel_launch(void* const* d_in, const int* in_sizes, int n_in,
                              void* d_out, int out_size, void* d_ws, size_t ws_size,
                              hipStream_t stream) {
    const float* x  = (const float*)d_in[0];
    const float* W1 = (const float*)d_in[1];
    const float* b1 = (const float*)d_in[2];
    const float* W2 = (const float*)d_in[3];
    const float* b2 = (const float*)d_in[4];
    const float* Ws = (const float*)d_in[5];
    const int*   ei = (const int*)d_in[6];   // [2, N_EDGES] row-major
    const int* src = ei;
    const int* dst = ei + N_EDGES;
    float* out = (float*)d_out;

    const int blk = 256;
    const int nblk_nodes = (N_NODES + blk - 1) / blk;

    int* hfix = (int*)d_ws;                         // [N] @ 0 (512KB reserved)
    const size_t base = 512 * 1024;

    mlp_kernel<<<nblk_nodes, blk, 0, stream>>>(x, W1, b1, W2, b2, hfix, N_NODES);

    // --- Primary: single-read partition path. -----------------------------
    const size_t curs_off = base;
    const size_t recs_off = base + 4096;
    const size_t recs_bytes = (size_t)NQBINS * GBINCAP * sizeof(unsigned);
    const size_t part_off = recs_off + recs_bytes;
    const size_t part_bytes = (size_t)NQBINS * NQBLK * QBIN * sizeof(unsigned);
    const size_t need_part = part_off + part_bytes;  // ~34 MiB

    if (ws_size >= need_part) {
        unsigned* cursor   = (unsigned*)((char*)d_ws + curs_off);
        unsigned* recs     = (unsigned*)((char*)d_ws + recs_off);
        unsigned* partials = (unsigned*)((char*)d_ws + part_off);

        (void)hipFuncSetAttribute(
            reinterpret_cast<const void*>(&partition_kernel),
            hipFuncAttributeMaxDynamicSharedMemorySize,
            NQBINS * LCAP * (int)sizeof(unsigned));

        hipMemsetAsync((void*)cursor, 0, NQBINS * sizeof(unsigned), stream);
        partition_kernel<<<PBLOCKS, PTHREADS,
                           NQBINS * LCAP * sizeof(unsigned), stream>>>(
            src, dst, hfix, recs, cursor);
        accumulate_kernel<<<NQBINS * NQBLK, QTHREADS, 0, stream>>>(
            recs, cursor, partials);
        finalize_part<<<nblk_nodes, blk, 0, stream>>>(partials, Ws, out, N_NODES);
        return;
    }

    // --- Fallback 1: 3 bins x 33792 (132KB dynamic LDS), G slices. --------
    constexpr int BIN3 = 33792;
    constexpr int NB3 = 3;
    (void)hipFuncSetAttribute(
        reinterpret_cast<const void*>(&scatter_binned<BIN3, NB3>),
        hipFuncAttributeMaxDynamicSharedMemorySize, BIN3 * sizeof(unsigned));
    unsigned* partials = (unsigned*)((char*)d_ws + base);
    const int cands3[3] = {80, 64, 32};
    for (int c = 0; c < 3; ++c) {
        int G3 = cands3[c];
        if (ws_size < base + (size_t)G3 * NB3 * BIN3 * sizeof(unsigned)) continue;
        int n4s = (N_EDGES / 4) / G3;
        scatter_binned<BIN3, NB3>
            <<<G3 * NB3, 1024, BIN3 * sizeof(unsigned), stream>>>(
                src, dst, hfix, partials, n4s);
        finalize_binned<BIN3, NB3><<<nblk_nodes, blk, 0, stream>>>(
            partials, Ws, out, N_NODES, G3);
        return;
    }

    // --- Fallback 2: packed u64 global atomics. ----------------------------
    unsigned long long* packed = (unsigned long long*)((char*)d_ws + base);
    hipMemsetAsync((void*)packed, 0, (size_t)N_NODES * sizeof(unsigned long long),
                   stream);
    scatter_atomic<<<2048, blk, 0, stream>>>(src, dst, hfix, packed);
    finalize_atomic<<<nblk_nodes, blk, 0, stream>>>(packed, Ws, out, N_NODES);
}

// Round 9
// 66.833 us; speedup vs baseline: 1.0145x; 1.0145x over previous
//
#include <hip/hip_runtime.h>

#define N_NODES 100000
#define N_EDGES 6400000

#define HSCALE 4096.0f           // 2^12 fixed point for h
#define HCLAMP 63.0f             // |hfix| <= 258048 < 2^18

// ---- Partition geometry (R6-proven shape, gather-free records) -------------
#define QBIN       4096          // nodes per bin (pow2 -> shift/mask)
#define QBIN_SHIFT 12
#define NQBINS     25            // 25*4096 = 102400 >= 100000
#define PBLOCKS    256           // 6250 quads per block, exact
#define PTHREADS   1024
#define LCAP       1280          // staging entries/bucket: mean 1000, +9 sigma
#define GBINCAP    270336        // records per bin: mean 256K, +28 sigma
#define NQBLK      20            // accumulate blocks per bin -> grid 500
#define QTHREADS   1024

typedef int int4v __attribute__((ext_vector_type(4)));

// ---------------------------------------------------------------------------
// Kernel A: per-node tiny MLP -> fixed-point int (scale 2^12, clamp +-63).
// ---------------------------------------------------------------------------
__global__ void mlp_kernel(const float* __restrict__ x,
                           const float* __restrict__ W1,
                           const float* __restrict__ b1,
                           const float* __restrict__ W2,
                           const float* __restrict__ b2,
                           int* __restrict__ hfix, int n) {
    int i = blockIdx.x * blockDim.x + threadIdx.x;
    if (i >= n) return;
    float xv = x[i];
    float acc = b2[0];
#pragma unroll
    for (int k = 0; k < 16; ++k) {
        float t = fmaxf(W1[k] * xv + b1[k], 0.0f);
        acc = fmaf(W2[k], t, acc);
    }
    acc = fminf(fmaxf(acc, -HCLAMP), HCLAMP);
    hfix[i] = __float2int_rn(acc * HSCALE);
}

// ---------------------------------------------------------------------------
// Pass P: single-read edge partition, NO GATHER.  rec = (src<<12)|(dst&4095)
// (17b + 12b = 29b).  Pure integer streaming: nontemporal int4 edge loads ->
// shift/or -> LDS bucket append.  125KB LDS staging -> 1 block/CU (R6 shape).
// ---------------------------------------------------------------------------
__global__ __launch_bounds__(PTHREADS)
void partition_kernel(const int* __restrict__ src,
                      const int* __restrict__ dst,
                      unsigned* __restrict__ recs,      // [NQBINS * GBINCAP]
                      unsigned* __restrict__ cursor) {  // [NQBINS], zeroed
    extern __shared__ unsigned sbuf[];                  // NQBINS * LCAP u32
    __shared__ unsigned scnt[NQBINS];
    __shared__ unsigned sbase[NQBINS];
    const int tid = threadIdx.x;
    if (tid < NQBINS) scnt[tid] = 0u;
    __syncthreads();

    const int quads = (N_EDGES / 4) / PBLOCKS;          // 6250 exact
    const int4v* __restrict__ s4 = (const int4v*)src + (size_t)blockIdx.x * quads;
    const int4v* __restrict__ d4 = (const int4v*)dst + (size_t)blockIdx.x * quads;

    for (int i = tid; i < quads; i += PTHREADS) {
        int4v d = __builtin_nontemporal_load(d4 + i);   // single-pass: bypass
        int4v s = __builtin_nontemporal_load(s4 + i);   // cache for edges
        int b0 = d.x >> QBIN_SHIFT, b1 = d.y >> QBIN_SHIFT;
        int b2 = d.z >> QBIN_SHIFT, b3 = d.w >> QBIN_SHIFT;
        unsigned rec0 = ((unsigned)s.x << 12) | (unsigned)(d.x & (QBIN - 1));
        unsigned rec1 = ((unsigned)s.y << 12) | (unsigned)(d.y & (QBIN - 1));
        unsigned rec2 = ((unsigned)s.z << 12) | (unsigned)(d.z & (QBIN - 1));
        unsigned rec3 = ((unsigned)s.w << 12) | (unsigned)(d.w & (QBIN - 1));
        unsigned sl0 = atomicAdd(&scnt[b0], 1u);
        unsigned sl1 = atomicAdd(&scnt[b1], 1u);
        unsigned sl2 = atomicAdd(&scnt[b2], 1u);
        unsigned sl3 = atomicAdd(&scnt[b3], 1u);
#define STORE(B, SL, REC)                                                     \
        if ((SL) < (unsigned)LCAP) {                                          \
            sbuf[(B) * LCAP + (SL)] = (REC);                                  \
        } else {                                                              \
            unsigned g = atomicAdd(&cursor[B], 1u);                           \
            if (g < (unsigned)GBINCAP) recs[(size_t)(B) * GBINCAP + g] = (REC);\
        }
        STORE(b0, sl0, rec0);
        STORE(b1, sl1, rec1);
        STORE(b2, sl2, rec2);
        STORE(b3, sl3, rec3);
#undef STORE
    }
    __syncthreads();

    // Reserve global ranges (25 atomics/block), flush buckets coalesced.
    if (tid < NQBINS) {
        unsigned m = min(scnt[tid], (unsigned)LCAP);
        sbase[tid] = atomicAdd(&cursor[tid], m);
    }
    __syncthreads();
    for (int b = 0; b < NQBINS; ++b) {
        unsigned m = min(scnt[b], (unsigned)LCAP);
        unsigned bs = sbase[b];
        for (unsigned t = tid; t < m; t += PTHREADS) {
            unsigned g = bs + t;
            if (g < (unsigned)GBINCAP)
                recs[(size_t)b * GBINCAP + g] = sbuf[b * LCAP + t];
        }
    }
}

// ---------------------------------------------------------------------------
// Pass Q: per-bin accumulation.  Coalesced rec reads; the hfix gather lives
// HERE (L2-resident 400KB, 512K threads of pure TLP to hide it).
// Packed u32 acc: sum(bits 8..31, two's complement) | count(bits 0..7).
// Per (node, block): count ~ Poisson(3.2) << 255; realistic |hfix| < 2^15
// -> |sum| << 2^23.
// ---------------------------------------------------------------------------
__global__ __launch_bounds__(QTHREADS)
void accumulate_kernel(const unsigned* __restrict__ recs,
                       const unsigned* __restrict__ cursor,
                       const int* __restrict__ hfix,
                       unsigned* __restrict__ partials) {
    __shared__ unsigned acc[QBIN];   // 16 KB
    const int b = blockIdx.x / NQBLK;
    const int j = blockIdx.x % NQBLK;
    const int tid = threadIdx.x;
    for (int k = tid; k < QBIN; k += QTHREADS) acc[k] = 0u;
    __syncthreads();

    const unsigned total = min(cursor[b], (unsigned)GBINCAP);
    const unsigned* __restrict__ base = recs + (size_t)b * GBINCAP;
    for (unsigned i = (unsigned)j * QTHREADS + tid; i < total;
         i += (unsigned)NQBLK * QTHREADS) {
        unsigned rec = base[i];
        unsigned srcn = rec >> 12;
        unsigned rel = rec & (QBIN - 1);
        int hf = hfix[srcn];
        atomicAdd(&acc[rel], (((unsigned)hf) << 8) + 1u);
    }
    __syncthreads();

    unsigned* __restrict__ outp = partials + (size_t)blockIdx.x * QBIN;
    for (int k = tid; k < QBIN; k += QTHREADS) outp[k] = acc[k];
}

// ---------------------------------------------------------------------------
// Pass F: reduce NQBLK partials per node, decode, mean, apply Ws.
// ---------------------------------------------------------------------------
__global__ void finalize_part(const unsigned* __restrict__ partials,
                              const float* __restrict__ Ws,
                              float* __restrict__ out, int n) {
    int i = blockIdx.x * blockDim.x + threadIdx.x;
    if (i >= n) return;
    const int bin = i >> QBIN_SHIFT;
    const int local = i & (QBIN - 1);
    int cnt = 0, sum = 0;
#pragma unroll
    for (int j = 0; j < NQBLK; ++j) {
        unsigned p = partials[(size_t)(bin * NQBLK + j) * QBIN + local];
        cnt += (int)(p & 0xFFu);
        sum += ((int)p) >> 8;
    }
    float mean = ((float)sum * (1.0f / HSCALE)) / (float)max(cnt, 1);
    float2 o;
    o.x = mean * Ws[0];
    o.y = mean * Ws[1];
    ((float2*)out)[i] = o;
}

// ===========================================================================
// Fallback 1: LDS-binned multi-pass scatter, 3 bins x 33792 (R5).
// ===========================================================================
template <int TBIN, int TNBINS>
__global__ __launch_bounds__(1024)
void scatter_binned(const int* __restrict__ src,
                    const int* __restrict__ dst,
                    const int* __restrict__ hfix,
                    unsigned* __restrict__ partials,
                    int n4_per_slice) {
    extern __shared__ unsigned acc[];
    const int bin   = blockIdx.x % TNBINS;
    const int slice = blockIdx.x / TNBINS;
    const int tid = threadIdx.x;
    for (int j = tid; j < TBIN; j += 1024) acc[j] = 0u;
    __syncthreads();
    const int bin_lo = bin * TBIN;
    const int4* __restrict__ s4 = (const int4*)src + (size_t)slice * n4_per_slice;
    const int4* __restrict__ d4 = (const int4*)dst + (size_t)slice * n4_per_slice;
#define PROC(dd, ss)                                                          \
    {                                                                         \
        unsigned r;                                                           \
        r = (unsigned)((dd).x - bin_lo);                                      \
        if (r < (unsigned)TBIN)                                               \
            atomicAdd(&acc[r], (((unsigned)hfix[(ss).x]) << 8) + 1u);         \
        r = (unsigned)((dd).y - bin_lo);                                      \
        if (r < (unsigned)TBIN)                                               \
            atomicAdd(&acc[r], (((unsigned)hfix[(ss).y]) << 8) + 1u);         \
        r = (unsigned)((dd).z - bin_lo);                                      \
        if (r < (unsigned)TBIN)                                               \
            atomicAdd(&acc[r], (((unsigned)hfix[(ss).z]) << 8) + 1u);         \
        r = (unsigned)((dd).w - bin_lo);                                      \
        if (r < (unsigned)TBIN)                                               \
            atomicAdd(&acc[r], (((unsigned)hfix[(ss).w]) << 8) + 1u);         \
    }
    for (int i = tid; i < n4_per_slice; i += 2048) {
        int4 d0 = d4[i];
        int4 s0 = s4[i];
        const int i1 = i + 1024;
        int4 d1, s1;
        const bool have1 = i1 < n4_per_slice;
        if (have1) { d1 = d4[i1]; s1 = s4[i1]; }
        PROC(d0, s0);
        if (have1) PROC(d1, s1);
    }
#undef PROC
    __syncthreads();
    unsigned* __restrict__ outp = partials + (size_t)blockIdx.x * TBIN;
    for (int j = tid; j < TBIN; j += 1024) outp[j] = acc[j];
}

template <int TBIN, int TNBINS>
__global__ void finalize_binned(const unsigned* __restrict__ partials,
                                const float* __restrict__ Ws,
                                float* __restrict__ out, int n, int nslices) {
    int i = blockIdx.x * blockDim.x + threadIdx.x;
    if (i >= n) return;
    const int bin = i / TBIN;
    const int local = i % TBIN;
    int cnt = 0, sum = 0;
    for (int s = 0; s < nslices; ++s) {
        unsigned p = partials[(size_t)(s * TNBINS + bin) * TBIN + local];
        cnt += (int)(p & 0xFFu);
        sum += ((int)p) >> 8;
    }
    float mean = ((float)sum * (1.0f / HSCALE)) / (float)max(cnt, 1);
    float2 o;
    o.x = mean * Ws[0];
    o.y = mean * Ws[1];
    ((float2*)out)[i] = o;
}

// ===========================================================================
// Fallback 2: one packed u64 global atomic per edge.
// ===========================================================================
__global__ void scatter_atomic(const int* __restrict__ src,
                               const int* __restrict__ dst,
                               const int* __restrict__ hfix,
                               unsigned long long* __restrict__ packed) {
    int tid = blockIdx.x * blockDim.x + threadIdx.x;
    int stride = gridDim.x * blockDim.x;
    const int4* __restrict__ src4 = (const int4*)src;
    const int4* __restrict__ dst4 = (const int4*)dst;
    const int n4 = N_EDGES / 4;
    for (int e = tid; e < n4; e += stride) {
        int4 s = src4[e];
        int4 d = dst4[e];
        long long h0 = hfix[s.x], h1 = hfix[s.y], h2 = hfix[s.z], h3 = hfix[s.w];
        atomicAdd(&packed[d.x], ((unsigned long long)(h0 << 20)) + 1ull);
        atomicAdd(&packed[d.y], ((unsigned long long)(h1 << 20)) + 1ull);
        atomicAdd(&packed[d.z], ((unsigned long long)(h2 << 20)) + 1ull);
        atomicAdd(&packed[d.w], ((unsigned long long)(h3 << 20)) + 1ull);
    }
}

__global__ void finalize_atomic(const unsigned long long* __restrict__ packed,
                                const float* __restrict__ Ws,
                                float* __restrict__ out, int n) {
    int i = blockIdx.x * blockDim.x + threadIdx.x;
    if (i >= n) return;
    long long p = (long long)packed[i];
    int cnt = (int)(p & 0xFFFFFll);
    long long sf = p >> 20;
    float mean = ((float)sf * (1.0f / HSCALE)) / (float)max(cnt, 1);
    float2 o;
    o.x = mean * Ws[0];
    o.y = mean * Ws[1];
    ((float2*)out)[i] = o;
}

extern "C" void kernel_launch(void* const* d_in, const int* in_sizes, int n_in,
                              void* d_out, int out_size, void* d_ws, size_t ws_size,
                              hipStream_t stream) {
    const float* x  = (const float*)d_in[0];
    const float* W1 = (const float*)d_in[1];
    const float* b1 = (const float*)d_in[2];
    const float* W2 = (const float*)d_in[3];
    const float* b2 = (const float*)d_in[4];
    const float* Ws = (const float*)d_in[5];
    const int*   ei = (const int*)d_in[6];   // [2, N_EDGES] row-major
    const int* src = ei;
    const int* dst = ei + N_EDGES;
    float* out = (float*)d_out;

    const int blk = 256;
    const int nblk_nodes = (N_NODES + blk - 1) / blk;

    int* hfix = (int*)d_ws;                         // [N] @ 0 (512KB reserved)
    const size_t base = 512 * 1024;

    mlp_kernel<<<nblk_nodes, blk, 0, stream>>>(x, W1, b1, W2, b2, hfix, N_NODES);

    // --- Primary: single-read gather-free partition path. -----------------
    const size_t curs_off = base;
    const size_t recs_off = base + 4096;
    const size_t recs_bytes = (size_t)NQBINS * GBINCAP * sizeof(unsigned);
    const size_t part_off = recs_off + recs_bytes;
    const size_t part_bytes = (size_t)NQBINS * NQBLK * QBIN * sizeof(unsigned);
    const size_t need_part = part_off + part_bytes;  // ~36 MiB

    if (ws_size >= need_part) {
        unsigned* cursor   = (unsigned*)((char*)d_ws + curs_off);
        unsigned* recs     = (unsigned*)((char*)d_ws + recs_off);
        unsigned* partials = (unsigned*)((char*)d_ws + part_off);

        (void)hipFuncSetAttribute(
            reinterpret_cast<const void*>(&partition_kernel),
            hipFuncAttributeMaxDynamicSharedMemorySize,
            NQBINS * LCAP * (int)sizeof(unsigned));

        hipMemsetAsync((void*)cursor, 0, NQBINS * sizeof(unsigned), stream);
        partition_kernel<<<PBLOCKS, PTHREADS,
                           NQBINS * LCAP * sizeof(unsigned), stream>>>(
            src, dst, recs, cursor);
        accumulate_kernel<<<NQBINS * NQBLK, QTHREADS, 0, stream>>>(
            recs, cursor, hfix, partials);
        finalize_part<<<nblk_nodes, blk, 0, stream>>>(partials, Ws, out, N_NODES);
        return;
    }

    // --- Fallback 1: 3 bins x 33792 (132KB dynamic LDS), G slices. --------
    constexpr int BIN3 = 33792;
    constexpr int NB3 = 3;
    (void)hipFuncSetAttribute(
        reinterpret_cast<const void*>(&scatter_binned<BIN3, NB3>),
        hipFuncAttributeMaxDynamicSharedMemorySize, BIN3 * sizeof(unsigned));
    unsigned* partials = (unsigned*)((char*)d_ws + base);
    const int cands3[3] = {80, 64, 32};
    for (int c = 0; c < 3; ++c) {
        int G3 = cands3[c];
        if (ws_size < base + (size_t)G3 * NB3 * BIN3 * sizeof(unsigned)) continue;
        int n4s = (N_EDGES / 4) / G3;
        scatter_binned<BIN3, NB3>
            <<<G3 * NB3, 1024, BIN3 * sizeof(unsigned), stream>>>(
                src, dst, hfix, partials, n4s);
        finalize_binned<BIN3, NB3><<<nblk_nodes, blk, 0, stream>>>(
            partials, Ws, out, N_NODES, G3);
        return;
    }

    // --- Fallback 2: packed u64 global atomics. ----------------------------
    unsigned long long* packed = (unsigned long long*)((char*)d_ws + base);
    hipMemsetAsync((void*)packed, 0, (size_t)N_NODES * sizeof(unsigned long long),
                   stream);
    scatter_atomic<<<2048, blk, 0, stream>>>(src, dst, hfix, packed);
    finalize_atomic<<<nblk_nodes, blk, 0, stream>>>(packed, Ws, out, N_NODES);
}

// Round 10
// 61.971 us; speedup vs baseline: 1.0941x; 1.0785x over previous
//
#include <hip/hip_runtime.h>

#define N_NODES 100000
#define N_EDGES 6400000

#define HSCALE 4096.0f           // 2^12 fixed point for h
#define HCLAMP 63.0f             // |hfix| <= 258048 < 2^18

// ---- Partition geometry (R6-proven shape, gather-free records) -------------
#define QBIN       4096          // nodes per bin (pow2 -> shift/mask)
#define QBIN_SHIFT 12
#define NQBINS     25            // 25*4096 = 102400 >= 100000
#define PBLOCKS    256           // 6250 quads per block, exact
#define PTHREADS   1024
#define LCAP       1280          // staging entries/bucket: mean 1000, +9 sigma
#define GBINCAP    270336        // records per bin: mean 256K, +28 sigma
#define NQBLK      20            // accumulate blocks per bin -> grid 500
#define QTHREADS   1024

typedef int int4v __attribute__((ext_vector_type(4)));

// ---------------------------------------------------------------------------
// Kernel A: per-node tiny MLP -> fixed-point int.  Also zeroes the partition
// cursors (replaces a whole memset dispatch in the captured graph).
// ---------------------------------------------------------------------------
__global__ void mlp_kernel(const float* __restrict__ x,
                           const float* __restrict__ W1,
                           const float* __restrict__ b1,
                           const float* __restrict__ W2,
                           const float* __restrict__ b2,
                           int* __restrict__ hfix,
                           unsigned* __restrict__ cursor, int n) {
    if (cursor && blockIdx.x == 0 && threadIdx.x < NQBINS)
        cursor[threadIdx.x] = 0u;
    int i = blockIdx.x * blockDim.x + threadIdx.x;
    if (i >= n) return;
    float xv = x[i];
    float acc = b2[0];
#pragma unroll
    for (int k = 0; k < 16; ++k) {
        float t = fmaxf(W1[k] * xv + b1[k], 0.0f);
        acc = fmaf(W2[k], t, acc);
    }
    acc = fminf(fmaxf(acc, -HCLAMP), HCLAMP);
    hfix[i] = __float2int_rn(acc * HSCALE);
}

// ---------------------------------------------------------------------------
// Pass P: single-read edge partition, NO GATHER.  rec = (src<<12)|(dst&4095).
// Cached loads (edge list is L3-resident across graph replays).  2 quads per
// iteration: all 4 int4 loads issue before any dependent op (2x chain ILP).
// ---------------------------------------------------------------------------
__global__ __launch_bounds__(PTHREADS)
void partition_kernel(const int* __restrict__ src,
                      const int* __restrict__ dst,
                      unsigned* __restrict__ recs,      // [NQBINS * GBINCAP]
                      unsigned* __restrict__ cursor) {  // [NQBINS], zeroed
    extern __shared__ unsigned sbuf[];                  // NQBINS * LCAP u32
    __shared__ unsigned scnt[NQBINS];
    __shared__ unsigned sbase[NQBINS];
    const int tid = threadIdx.x;
    if (tid < NQBINS) scnt[tid] = 0u;
    __syncthreads();

    const int quads = (N_EDGES / 4) / PBLOCKS;          // 6250 exact
    const int4v* __restrict__ s4 = (const int4v*)src + (size_t)blockIdx.x * quads;
    const int4v* __restrict__ d4 = (const int4v*)dst + (size_t)blockIdx.x * quads;

#define PROC(D, S)                                                            \
    {                                                                         \
        int b0 = (D).x >> QBIN_SHIFT, b1 = (D).y >> QBIN_SHIFT;               \
        int b2 = (D).z >> QBIN_SHIFT, b3 = (D).w >> QBIN_SHIFT;               \
        unsigned r0 = ((unsigned)(S).x << 12) | (unsigned)((D).x & (QBIN-1)); \
        unsigned r1 = ((unsigned)(S).y << 12) | (unsigned)((D).y & (QBIN-1)); \
        unsigned r2 = ((unsigned)(S).z << 12) | (unsigned)((D).z & (QBIN-1)); \
        unsigned r3 = ((unsigned)(S).w << 12) | (unsigned)((D).w & (QBIN-1)); \
        unsigned sl0 = atomicAdd(&scnt[b0], 1u);                              \
        unsigned sl1 = atomicAdd(&scnt[b1], 1u);                              \
        unsigned sl2 = atomicAdd(&scnt[b2], 1u);                              \
        unsigned sl3 = atomicAdd(&scnt[b3], 1u);                              \
        if (sl0 < (unsigned)LCAP) sbuf[b0 * LCAP + sl0] = r0;                 \
        else {                                                                \
            unsigned g = atomicAdd(&cursor[b0], 1u);                          \
            if (g < (unsigned)GBINCAP) recs[(size_t)b0 * GBINCAP + g] = r0;   \
        }                                                                     \
        if (sl1 < (unsigned)LCAP) sbuf[b1 * LCAP + sl1] = r1;                 \
        else {                                                                \
            unsigned g = atomicAdd(&cursor[b1], 1u);                          \
            if (g < (unsigned)GBINCAP) recs[(size_t)b1 * GBINCAP + g] = r1;   \
        }                                                                     \
        if (sl2 < (unsigned)LCAP) sbuf[b2 * LCAP + sl2] = r2;                 \
        else {                                                                \
            unsigned g = atomicAdd(&cursor[b2], 1u);                          \
            if (g < (unsigned)GBINCAP) recs[(size_t)b2 * GBINCAP + g] = r2;   \
        }                                                                     \
        if (sl3 < (unsigned)LCAP) sbuf[b3 * LCAP + sl3] = r3;                 \
        else {                                                                \
            unsigned g = atomicAdd(&cursor[b3], 1u);                          \
            if (g < (unsigned)GBINCAP) recs[(size_t)b3 * GBINCAP + g] = r3;   \
        }                                                                     \
    }

    for (int i = tid; i < quads; i += 2 * PTHREADS) {
        int4v d0 = d4[i];
        int4v s0 = s4[i];
        const int i1 = i + PTHREADS;
        const bool have1 = i1 < quads;
        int4v d1, s1;
        if (have1) { d1 = d4[i1]; s1 = s4[i1]; }
        PROC(d0, s0);
        if (have1) PROC(d1, s1);
    }
#undef PROC
    __syncthreads();

    // Reserve global ranges (25 atomics/block), flush buckets coalesced.
    if (tid < NQBINS) {
        unsigned m = min(scnt[tid], (unsigned)LCAP);
        sbase[tid] = atomicAdd(&cursor[tid], m);
    }
    __syncthreads();
    for (int b = 0; b < NQBINS; ++b) {
        unsigned m = min(scnt[b], (unsigned)LCAP);
        unsigned bs = sbase[b];
        for (unsigned t = tid; t < m; t += PTHREADS) {
            unsigned g = bs + t;
            if (g < (unsigned)GBINCAP)
                recs[(size_t)b * GBINCAP + g] = sbuf[b * LCAP + t];
        }
    }
}

// ---------------------------------------------------------------------------
// Pass Q: per-bin accumulation.  2 records per iteration: both gathers issue
// before either LDS atomic (2x chain ILP).  Packed u32 acc: sum 24b | cnt 8b.
// ---------------------------------------------------------------------------
__global__ __launch_bounds__(QTHREADS)
void accumulate_kernel(const unsigned* __restrict__ recs,
                       const unsigned* __restrict__ cursor,
                       const int* __restrict__ hfix,
                       unsigned* __restrict__ partials) {
    __shared__ unsigned acc[QBIN];   // 16 KB
    const int b = blockIdx.x / NQBLK;
    const int j = blockIdx.x % NQBLK;
    const int tid = threadIdx.x;
    for (int k = tid; k < QBIN; k += QTHREADS) acc[k] = 0u;
    __syncthreads();

    const unsigned total = min(cursor[b], (unsigned)GBINCAP);
    const unsigned* __restrict__ base = recs + (size_t)b * GBINCAP;
    const unsigned stride = (unsigned)NQBLK * QTHREADS;
    for (unsigned i = (unsigned)j * QTHREADS + tid; i < total; i += 2 * stride) {
        unsigned rec0 = base[i];
        const unsigned i1 = i + stride;
        const bool have1 = i1 < total;
        unsigned rec1 = have1 ? base[i1] : 0u;
        int hf0 = hfix[rec0 >> 12];
        int hf1 = have1 ? hfix[rec1 >> 12] : 0;
        atomicAdd(&acc[rec0 & (QBIN - 1)], (((unsigned)hf0) << 8) + 1u);
        if (have1)
            atomicAdd(&acc[rec1 & (QBIN - 1)], (((unsigned)hf1) << 8) + 1u);
    }
    __syncthreads();

    unsigned* __restrict__ outp = partials + (size_t)blockIdx.x * QBIN;
    for (int k = tid; k < QBIN; k += QTHREADS) outp[k] = acc[k];
}

// ---------------------------------------------------------------------------
// Pass F: reduce NQBLK partials per node, decode, mean, apply Ws.
// ---------------------------------------------------------------------------
__global__ void finalize_part(const unsigned* __restrict__ partials,
                              const float* __restrict__ Ws,
                              float* __restrict__ out, int n) {
    int i = blockIdx.x * blockDim.x + threadIdx.x;
    if (i >= n) return;
    const int bin = i >> QBIN_SHIFT;
    const int local = i & (QBIN - 1);
    int cnt = 0, sum = 0;
#pragma unroll
    for (int j = 0; j < NQBLK; ++j) {
        unsigned p = partials[(size_t)(bin * NQBLK + j) * QBIN + local];
        cnt += (int)(p & 0xFFu);
        sum += ((int)p) >> 8;
    }
    float mean = ((float)sum * (1.0f / HSCALE)) / (float)max(cnt, 1);
    float2 o;
    o.x = mean * Ws[0];
    o.y = mean * Ws[1];
    ((float2*)out)[i] = o;
}

// ===========================================================================
// Fallback 1: LDS-binned multi-pass scatter, 3 bins x 33792 (R5).
// ===========================================================================
template <int TBIN, int TNBINS>
__global__ __launch_bounds__(1024)
void scatter_binned(const int* __restrict__ src,
                    const int* __restrict__ dst,
                    const int* __restrict__ hfix,
                    unsigned* __restrict__ partials,
                    int n4_per_slice) {
    extern __shared__ unsigned acc[];
    const int bin   = blockIdx.x % TNBINS;
    const int slice = blockIdx.x / TNBINS;
    const int tid = threadIdx.x;
    for (int j = tid; j < TBIN; j += 1024) acc[j] = 0u;
    __syncthreads();
    const int bin_lo = bin * TBIN;
    const int4* __restrict__ s4 = (const int4*)src + (size_t)slice * n4_per_slice;
    const int4* __restrict__ d4 = (const int4*)dst + (size_t)slice * n4_per_slice;
#define PROC(dd, ss)                                                          \
    {                                                                         \
        unsigned r;                                                           \
        r = (unsigned)((dd).x - bin_lo);                                      \
        if (r < (unsigned)TBIN)                                               \
            atomicAdd(&acc[r], (((unsigned)hfix[(ss).x]) << 8) + 1u);         \
        r = (unsigned)((dd).y - bin_lo);                                      \
        if (r < (unsigned)TBIN)                                               \
            atomicAdd(&acc[r], (((unsigned)hfix[(ss).y]) << 8) + 1u);         \
        r = (unsigned)((dd).z - bin_lo);                                      \
        if (r < (unsigned)TBIN)                                               \
            atomicAdd(&acc[r], (((unsigned)hfix[(ss).z]) << 8) + 1u);         \
        r = (unsigned)((dd).w - bin_lo);                                      \
        if (r < (unsigned)TBIN)                                               \
            atomicAdd(&acc[r], (((unsigned)hfix[(ss).w]) << 8) + 1u);         \
    }
    for (int i = tid; i < n4_per_slice; i += 2048) {
        int4 d0 = d4[i];
        int4 s0 = s4[i];
        const int i1 = i + 1024;
        int4 d1, s1;
        const bool have1 = i1 < n4_per_slice;
        if (have1) { d1 = d4[i1]; s1 = s4[i1]; }
        PROC(d0, s0);
        if (have1) PROC(d1, s1);
    }
#undef PROC
    __syncthreads();
    unsigned* __restrict__ outp = partials + (size_t)blockIdx.x * TBIN;
    for (int j = tid; j < TBIN; j += 1024) outp[j] = acc[j];
}

template <int TBIN, int TNBINS>
__global__ void finalize_binned(const unsigned* __restrict__ partials,
                                const float* __restrict__ Ws,
                                float* __restrict__ out, int n, int nslices) {
    int i = blockIdx.x * blockDim.x + threadIdx.x;
    if (i >= n) return;
    const int bin = i / TBIN;
    const int local = i % TBIN;
    int cnt = 0, sum = 0;
    for (int s = 0; s < nslices; ++s) {
        unsigned p = partials[(size_t)(s * TNBINS + bin) * TBIN + local];
        cnt += (int)(p & 0xFFu);
        sum += ((int)p) >> 8;
    }
    float mean = ((float)sum * (1.0f / HSCALE)) / (float)max(cnt, 1);
    float2 o;
    o.x = mean * Ws[0];
    o.y = mean * Ws[1];
    ((float2*)out)[i] = o;
}

// ===========================================================================
// Fallback 2: one packed u64 global atomic per edge.
// ===========================================================================
__global__ void scatter_atomic(const int* __restrict__ src,
                               const int* __restrict__ dst,
                               const int* __restrict__ hfix,
                               unsigned long long* __restrict__ packed) {
    int tid = blockIdx.x * blockDim.x + threadIdx.x;
    int stride = gridDim.x * blockDim.x;
    const int4* __restrict__ src4 = (const int4*)src;
    const int4* __restrict__ dst4 = (const int4*)dst;
    const int n4 = N_EDGES / 4;
    for (int e = tid; e < n4; e += stride) {
        int4 s = src4[e];
        int4 d = dst4[e];
        long long h0 = hfix[s.x], h1 = hfix[s.y], h2 = hfix[s.z], h3 = hfix[s.w];
        atomicAdd(&packed[d.x], ((unsigned long long)(h0 << 20)) + 1ull);
        atomicAdd(&packed[d.y], ((unsigned long long)(h1 << 20)) + 1ull);
        atomicAdd(&packed[d.z], ((unsigned long long)(h2 << 20)) + 1ull);
        atomicAdd(&packed[d.w], ((unsigned long long)(h3 << 20)) + 1ull);
    }
}

__global__ void finalize_atomic(const unsigned long long* __restrict__ packed,
                                const float* __restrict__ Ws,
                                float* __restrict__ out, int n) {
    int i = blockIdx.x * blockDim.x + threadIdx.x;
    if (i >= n) return;
    long long p = (long long)packed[i];
    int cnt = (int)(p & 0xFFFFFll);
    long long sf = p >> 20;
    float mean = ((float)sf * (1.0f / HSCALE)) / (float)max(cnt, 1);
    float2 o;
    o.x = mean * Ws[0];
    o.y = mean * Ws[1];
    ((float2*)out)[i] = o;
}

extern "C" void kernel_launch(void* const* d_in, const int* in_sizes, int n_in,
                              void* d_out, int out_size, void* d_ws, size_t ws_size,
                              hipStream_t stream) {
    const float* x  = (const float*)d_in[0];
    const float* W1 = (const float*)d_in[1];
    const float* b1 = (const float*)d_in[2];
    const float* W2 = (const float*)d_in[3];
    const float* b2 = (const float*)d_in[4];
    const float* Ws = (const float*)d_in[5];
    const int*   ei = (const int*)d_in[6];   // [2, N_EDGES] row-major
    const int* src = ei;
    const int* dst = ei + N_EDGES;
    float* out = (float*)d_out;

    const int blk = 256;
    const int nblk_nodes = (N_NODES + blk - 1) / blk;

    int* hfix = (int*)d_ws;                         // [N] @ 0 (512KB reserved)
    const size_t base = 512 * 1024;

    // --- Primary-path layout & feasibility (decided before mlp launch). ---
    const size_t curs_off = base;
    const size_t recs_off = base + 4096;
    const size_t recs_bytes = (size_t)NQBINS * GBINCAP * sizeof(unsigned);
    const size_t part_off = recs_off + recs_bytes;
    const size_t part_bytes = (size_t)NQBINS * NQBLK * QBIN * sizeof(unsigned);
    const size_t need_part = part_off + part_bytes;  // ~36 MiB
    const bool primary = (ws_size >= need_part);

    unsigned* cursor = primary ? (unsigned*)((char*)d_ws + curs_off) : nullptr;

    mlp_kernel<<<nblk_nodes, blk, 0, stream>>>(x, W1, b1, W2, b2, hfix,
                                               cursor, N_NODES);

    if (primary) {
        unsigned* recs     = (unsigned*)((char*)d_ws + recs_off);
        unsigned* partials = (unsigned*)((char*)d_ws + part_off);

        (void)hipFuncSetAttribute(
            reinterpret_cast<const void*>(&partition_kernel),
            hipFuncAttributeMaxDynamicSharedMemorySize,
            NQBINS * LCAP * (int)sizeof(unsigned));

        partition_kernel<<<PBLOCKS, PTHREADS,
                           NQBINS * LCAP * sizeof(unsigned), stream>>>(
            src, dst, recs, cursor);
        accumulate_kernel<<<NQBINS * NQBLK, QTHREADS, 0, stream>>>(
            recs, cursor, hfix, partials);
        finalize_part<<<nblk_nodes, blk, 0, stream>>>(partials, Ws, out, N_NODES);
        return;
    }

    // --- Fallback 1: 3 bins x 33792 (132KB dynamic LDS), G slices. --------
    constexpr int BIN3 = 33792;
    constexpr int NB3 = 3;
    (void)hipFuncSetAttribute(
        reinterpret_cast<const void*>(&scatter_binned<BIN3, NB3>),
        hipFuncAttributeMaxDynamicSharedMemorySize, BIN3 * sizeof(unsigned));
    unsigned* partials = (unsigned*)((char*)d_ws + base);
    const int cands3[3] = {80, 64, 32};
    for (int c = 0; c < 3; ++c) {
        int G3 = cands3[c];
        if (ws_size < base + (size_t)G3 * NB3 * BIN3 * sizeof(unsigned)) continue;
        int n4s = (N_EDGES / 4) / G3;
        scatter_binned<BIN3, NB3>
            <<<G3 * NB3, 1024, BIN3 * sizeof(unsigned), stream>>>(
                src, dst, hfix, partials, n4s);
        finalize_binned<BIN3, NB3><<<nblk_nodes, blk, 0, stream>>>(
            partials, Ws, out, N_NODES, G3);
        return;
    }

    // --- Fallback 2: packed u64 global atomics. ----------------------------
    unsigned long long* packed = (unsigned long long*)((char*)d_ws + base);
    hipMemsetAsync((void*)packed, 0, (size_t)N_NODES * sizeof(unsigned long long),
                   stream);
    scatter_atomic<<<2048, blk, 0, stream>>>(src, dst, hfix, packed);
    finalize_atomic<<<nblk_nodes, blk, 0, stream>>>(packed, Ws, out, N_NODES);
}